// Round 4
// baseline (150.908 us; speedup 1.0000x reference)
//
#include <hip/hip_runtime.h>

#define SEQ 79
#define DM 1024
#define BATCHN 512
#define NROWS (BATCHN * SEQ)        // 40448
#define NPB (SEQ * SEQ)             // 6241 pairs per batch
#define WS_PER_B 5200               // u4[8][80][4] + v4[8][80][4] + col[80]
#define TILES_PER_B 4
#define CHUNK 1561                  // ceil(6241/4)

// ---------------- K1: per-(b,n) row -> u'[32], v'[32], color -------------
// One wave per row; coalesced float4 x-loads; butterfly reduce; lanes 0..31
// produce u'_k, lanes 32..63 v'_k. Store into ws[b] with the float4-friendly
// [k>>2][n][k&3] layout k2 wants in LDS.
__global__ __launch_bounds__(256) void k1_embed(
    const float* __restrict__ x,
    const float* __restrict__ piece_w, const float* __restrict__ piece_b,
    const float* __restrict__ color_w, const float* __restrict__ color_b,
    const float* __restrict__ mlp1_w,  const float* __restrict__ mlp1_b,
    float* __restrict__ ws)
{
    const int lane = threadIdx.x & 63;
    const int wid  = (blockIdx.x * blockDim.x + threadIdx.x) >> 6;
    const int nw   = (gridDim.x * blockDim.x) >> 6;
    const int k    = lane & 31;
    const bool is_u = (lane < 32);

    float wp[4][4][7];
#pragma unroll
    for (int q = 0; q < 4; ++q)
#pragma unroll
        for (int t = 0; t < 4; ++t) {
            const int c = q * 256 + lane * 4 + t;
#pragma unroll
            for (int e = 0; e < 6; ++e) wp[q][t][e] = piece_w[c * 6 + e];
            wp[q][t][6] = color_w[c];
        }

    float wsp0 = mlp1_w[0 * 32 + k];
    float wsp1 = mlp1_w[1 * 32 + k];
    if (!is_u) { wsp0 = -wsp0; wsp1 = -wsp1; }
    const float bias1 = is_u ? mlp1_b[k] : 0.0f;
    float wc[6];
#pragma unroll
    for (int c = 0; c < 6; ++c)
        wc[c] = mlp1_w[((is_u ? 2 : 8) + c) * 32 + k];

    float pb[6];
#pragma unroll
    for (int e = 0; e < 6; ++e) pb[e] = piece_b[e];
    const float cb = color_b[0];

    for (int row = wid; row < NROWS; row += nw) {
        const float4* xr = (const float4*)(x + (size_t)row * DM);
        float4 xv[4];
#pragma unroll
        for (int q = 0; q < 4; ++q) xv[q] = xr[q * 64 + lane];

        float acc[7] = {0.f, 0.f, 0.f, 0.f, 0.f, 0.f, 0.f};
#pragma unroll
        for (int q = 0; q < 4; ++q) {
            const float xs[4] = {xv[q].x, xv[q].y, xv[q].z, xv[q].w};
#pragma unroll
            for (int t = 0; t < 4; ++t)
#pragma unroll
                for (int e = 0; e < 7; ++e)
                    acc[e] = fmaf(xs[t], wp[q][t][e], acc[e]);
        }

#pragma unroll
        for (int e = 0; e < 7; ++e) {
#pragma unroll
            for (int m = 32; m >= 1; m >>= 1)
                acc[e] += __shfl_xor(acc[e], m, 64);
        }

        float p[6];
#pragma unroll
        for (int e = 0; e < 6; ++e) p[e] = acc[e] + pb[e];

        const int b = row / SEQ;
        const int n = row - b * SEQ;
        const float fx = (n < 64) ? (float)(n >> 3) : 0.0f;
        const float fy = (n < 64) ? (float)(n & 7) : 0.0f;

        float val = bias1;
        val = fmaf(fx, wsp0, val);
        val = fmaf(fy, wsp1, val);
#pragma unroll
        for (int c = 0; c < 6; ++c) val = fmaf(p[c], wc[c], val);

        float* wb = ws + (size_t)b * WS_PER_B + (is_u ? 0 : 2560);
        wb[(k >> 2) * 320 + n * 4 + (k & 3)] = val;
        if (lane == 0) ws[(size_t)b * WS_PER_B + 5120 + n] = acc[6] + cb;
    }
}

// ---------------- K2: pair MLP, 4 blocks per batch ------------------------
__device__ __forceinline__ float gelu_fast(float a) {
    // 0.5*a*(1+tanh(0.79788456*(a+0.044715*a^3))) = a - a/(exp2(c1*a+c2*a^3)+1)
    const float c1 = 2.3022585093f;   // 2*0.7978845608*log2(e)
    const float c2 = 0.1029450750f;   // c1*0.044715
    const float t  = a * fmaf(a * a, c2, c1);
    const float e  = __builtin_amdgcn_exp2f(t);
    const float r  = __builtin_amdgcn_rcpf(e + 1.0f);
    return fmaf(-a, r, a);
}

__global__ __launch_bounds__(256) void k2_pair(
    const float* __restrict__ ws,
    const float* __restrict__ mlp1_w,
    const float* __restrict__ mlp2_w, const float* __restrict__ mlp2_b,
    float* __restrict__ out)
{
    __shared__ float lds[WS_PER_B];   // 20.8 KB -> 7 blocks/CU

    const int b = blockIdx.x >> 2;
    const int q = blockIdx.x & 3;

    // stage batch b's u/v/col from ws (L2/L3-resident) into LDS
    {
        const float4* src = (const float4*)(ws + (size_t)b * WS_PER_B);
        float4* dst = (float4*)lds;
        for (int t = threadIdx.x; t < WS_PER_B / 4; t += 256) dst[t] = src[t];
    }
    __syncthreads();

    const float4* uS4 = (const float4*)lds;          // [8][80]
    const float4* vS4 = (const float4*)(lds + 2560); // [8][80]
    const float*  colS = lds + 5120;

    const int start = q * CHUNK;
    const int end   = (start + CHUNK < NPB) ? start + CHUNK : NPB;
    const size_t ob = (size_t)b * (8 * NPB);

    for (int p = start + (int)threadIdx.x; p < end; p += 256) {
        const unsigned i = (unsigned)p / 79u;
        const unsigned j = (unsigned)p - i * 79u;
        const float same = (colS[i] == colS[j]) ? 1.0f : 0.0f;

        float acc2[8] = {0.f, 0.f, 0.f, 0.f, 0.f, 0.f, 0.f, 0.f};
#pragma unroll
        for (int kq = 0; kq < 8; ++kq) {
            const float4 u4 = uS4[kq * 80 + i];      // broadcast (i ~uniform)
            const float4 v4 = vS4[kq * 80 + j];      // stride-1, conflict-free
            const float ua[4] = {u4.x, u4.y, u4.z, u4.w};
            const float va[4] = {v4.x, v4.y, v4.z, v4.w};
#pragma unroll
            for (int t = 0; t < 4; ++t) {
                const int kk = kq * 4 + t;
                float a = ua[t] + va[t];
                a = fmaf(same, mlp1_w[14 * 32 + kk], a);        // s_load
                const float h = gelu_fast(a);
#pragma unroll
                for (int e = 0; e < 8; ++e)
                    acc2[e] = fmaf(h, mlp2_w[kk * 8 + e], acc2[e]);  // s_load
            }
        }

#pragma unroll
        for (int e = 0; e < 8; ++e)
            out[ob + (size_t)e * NPB + p] = acc2[e] + mlp2_b[e];
    }
}

extern "C" void kernel_launch(void* const* d_in, const int* in_sizes, int n_in,
                              void* d_out, int out_size, void* d_ws, size_t ws_size,
                              hipStream_t stream) {
    const float* x       = (const float*)d_in[0];
    const float* piece_w = (const float*)d_in[1];
    const float* piece_b = (const float*)d_in[2];
    const float* color_w = (const float*)d_in[3];
    const float* color_b = (const float*)d_in[4];
    const float* mlp1_w  = (const float*)d_in[5];
    const float* mlp1_b  = (const float*)d_in[6];
    const float* mlp2_w  = (const float*)d_in[7];
    const float* mlp2_b  = (const float*)d_in[8];
    float* out = (float*)d_out;
    float* ws  = (float*)d_ws;   // needs 512*5200*4 = 10.65 MB

    hipLaunchKernelGGL(k1_embed, dim3(2048), dim3(256), 0, stream,
                       x, piece_w, piece_b, color_w, color_b, mlp1_w, mlp1_b, ws);
    hipLaunchKernelGGL(k2_pair, dim3(BATCHN * TILES_PER_B), dim3(256), 0, stream,
                       ws, mlp1_w, mlp2_w, mlp2_b, out);
}

// Round 6
// 86.550 us; speedup vs baseline: 1.7436x; 1.7436x over previous
//
#include <hip/hip_runtime.h>

#define SEQ 79
#define DM 1024
#define BATCHN 512
#define NROWS (BATCHN * SEQ)        // 40448
#define NPB (SEQ * SEQ)             // 6241
#define P 36                        // k-pitch in floats (bank-friendly, 16B aligned)
#define UOFF 0
#define VOFF (SEQ * P)              // 2844
#define COFF2 (2 * SEQ * P)         // 5688
#define WS_PER_B 5776               // padded to /16; 23.1 KB per batch
#define NTILES 395                  // 79 i * 5 j-tiles of 16 (last tile: 15 valid j)

typedef float v2f  __attribute__((ext_vector_type(2)));
typedef float f32x4 __attribute__((ext_vector_type(4)));
typedef short short8 __attribute__((ext_vector_type(8)));

// ---------------- K1: per-(b,n) row -> u'[32], v'[32], color -------------
// One wave per row; coalesced float4 x-loads; butterfly reduce; lanes 0..31
// produce u'_k, lanes 32..63 v'_k. ws[b]: u[n][k] pitch 36, v at +VOFF,
// col at +COFF2.
__global__ __launch_bounds__(256) void k1_embed(
    const float* __restrict__ x,
    const float* __restrict__ piece_w, const float* __restrict__ piece_b,
    const float* __restrict__ color_w, const float* __restrict__ color_b,
    const float* __restrict__ mlp1_w,  const float* __restrict__ mlp1_b,
    float* __restrict__ ws)
{
    const int lane = threadIdx.x & 63;
    const int wid  = (blockIdx.x * blockDim.x + threadIdx.x) >> 6;
    const int nw   = (gridDim.x * blockDim.x) >> 6;
    const int k    = lane & 31;
    const bool is_u = (lane < 32);

    float wp[4][4][7];
#pragma unroll
    for (int q = 0; q < 4; ++q)
#pragma unroll
        for (int t = 0; t < 4; ++t) {
            const int c = q * 256 + lane * 4 + t;
#pragma unroll
            for (int e = 0; e < 6; ++e) wp[q][t][e] = piece_w[c * 6 + e];
            wp[q][t][6] = color_w[c];
        }

    float wsp0 = mlp1_w[0 * 32 + k];
    float wsp1 = mlp1_w[1 * 32 + k];
    if (!is_u) { wsp0 = -wsp0; wsp1 = -wsp1; }
    const float bias1 = is_u ? mlp1_b[k] : 0.0f;
    float wc[6];
#pragma unroll
    for (int c = 0; c < 6; ++c)
        wc[c] = mlp1_w[((is_u ? 2 : 8) + c) * 32 + k];

    float pb[6];
#pragma unroll
    for (int e = 0; e < 6; ++e) pb[e] = piece_b[e];
    const float cb = color_b[0];

    for (int row = wid; row < NROWS; row += nw) {
        const float4* xr = (const float4*)(x + (size_t)row * DM);
        float4 xv[4];
#pragma unroll
        for (int q = 0; q < 4; ++q) xv[q] = xr[q * 64 + lane];

        float acc[7] = {0.f, 0.f, 0.f, 0.f, 0.f, 0.f, 0.f};
#pragma unroll
        for (int q = 0; q < 4; ++q) {
            const float xs[4] = {xv[q].x, xv[q].y, xv[q].z, xv[q].w};
#pragma unroll
            for (int t = 0; t < 4; ++t)
#pragma unroll
                for (int e = 0; e < 7; ++e)
                    acc[e] = fmaf(xs[t], wp[q][t][e], acc[e]);
        }

#pragma unroll
        for (int e = 0; e < 7; ++e) {
#pragma unroll
            for (int m = 32; m >= 1; m >>= 1)
                acc[e] += __shfl_xor(acc[e], m, 64);
        }

        float p[6];
#pragma unroll
        for (int e = 0; e < 6; ++e) p[e] = acc[e] + pb[e];

        const int b = row / SEQ;
        const int n = row - b * SEQ;
        const float fx = (n < 64) ? (float)(n >> 3) : 0.0f;
        const float fy = (n < 64) ? (float)(n & 7) : 0.0f;

        float val = bias1;
        val = fmaf(fx, wsp0, val);
        val = fmaf(fy, wsp1, val);
#pragma unroll
        for (int c = 0; c < 6; ++c) val = fmaf(p[c], wc[c], val);

        ws[(size_t)b * WS_PER_B + (is_u ? UOFF : VOFF) + n * P + k] = val;
        if (lane == 0) ws[(size_t)b * WS_PER_B + COFF2 + n] = acc[6] + cb;
    }
}

// ---------------- K2: 16-pair tiles, packed gelu + MFMA layer-2 ----------
__device__ __forceinline__ unsigned cvt_pk_bf16(float lo, float hi) {
    unsigned r;
    asm("v_cvt_pk_bf16_f32 %0, %1, %2" : "=v"(r) : "v"(lo), "v"(hi));
    return r;
}

__device__ __forceinline__ v2f gelu2(v2f a) {
    // gelu(a) = a - a / (exp2(c1*a + c2*a^3) + 1)
    const v2f C1 = {2.3022585093f, 2.3022585093f};
    const v2f C2 = {0.1029450750f, 0.1029450750f};
    v2f tt = a * (a * a * C2 + C1);
    v2f e;
    e.x = __builtin_amdgcn_exp2f(tt.x);
    e.y = __builtin_amdgcn_exp2f(tt.y);
    v2f ep = e + (v2f){1.f, 1.f};
    v2f r;
    r.x = __builtin_amdgcn_rcpf(ep.x);
    r.y = __builtin_amdgcn_rcpf(ep.y);
    return a - a * r;
}

__global__ __launch_bounds__(256, 6) void k2_pair(
    const float* __restrict__ ws,
    const float* __restrict__ mlp1_w,
    const float* __restrict__ mlp2_w, const float* __restrict__ mlp2_b,
    float* __restrict__ out)
{
    __shared__ float lds[WS_PER_B];     // 23104 B -> 7 blocks/CU

    const int tid  = threadIdx.x;
    const int lane = tid & 63;
    const int wv   = tid >> 6;
    const int blk  = blockIdx.x;
    const int b    = blk / 3;
    const int qq   = blk - 3 * b;

    const int e16 = lane & 15;          // tile column (j offset / output e)
    const int kq  = lane >> 4;          // k-quarter
    const int k0  = kq * 8;

    // ---- prepack A-frag = W2^T[e][k] in bf16 (elem q<->k0+q, word w: 2w,2w+1)
    union { unsigned w[4]; short8 s; } A;
#pragma unroll
    for (int w = 0; w < 4; ++w) {
        const float lo = (e16 < 8) ? mlp2_w[(k0 + 2 * w) * 8 + e16] : 0.0f;
        const float hi = (e16 < 8) ? mlp2_w[(k0 + 2 * w + 1) * 8 + e16] : 0.0f;
        A.w[w] = cvt_pk_bf16(lo, hi);
    }
    // w14 pairs for this lane's k-slice
    v2f w14p[4];
#pragma unroll
    for (int w = 0; w < 4; ++w)
        w14p[w] = (v2f){mlp1_w[14 * 32 + k0 + 2 * w], mlp1_w[14 * 32 + k0 + 2 * w + 1]};
    // layer-2 bias for this lane's output rows (e = kq*4+q), valid when kq<2
    float b2v[4];
#pragma unroll
    for (int q = 0; q < 4; ++q)
        b2v[q] = (kq < 2) ? mlp2_b[kq * 4 + q] : 0.0f;

    // ---- stage ws[b] (23.1 KB) into LDS
    {
        const float4* src = (const float4*)(ws + (size_t)b * WS_PER_B);
        float4* dst = (float4*)lds;
#pragma unroll
        for (int s = 0; s < WS_PER_B / 4 / 256 + 1; ++s) {
            const int idx = tid + s * 256;
            if (idx < WS_PER_B / 4) dst[idx] = src[idx];
        }
    }
    __syncthreads();

    const float* uS = lds + UOFF;
    const float* vS = lds + VOFF;
    const float* cS = lds + COFF2;

    const int tstart = qq * 132;
    const int tend   = (qq == 2) ? NTILES : tstart + 132;
    const size_t obb = (size_t)b * (8 * NPB);

    for (int t = tstart + wv; t < tend; t += 4) {
        const int i  = t / 5;                  // wave-uniform
        const int jt = t - i * 5;
        const int j  = jt * 16 + e16;          // may be 79 (padding) on last tile

        const float4 ua = *(const float4*)(uS + i * P + k0);      // broadcast
        const float4 ub = *(const float4*)(uS + i * P + k0 + 4);
        const float4 va = *(const float4*)(vS + j * P + k0);      // 2-way, free
        const float4 vb = *(const float4*)(vS + j * P + k0 + 4);

        const float sw = (cS[i] == cS[j]) ? 1.0f : 0.0f;
        const v2f swp = {sw, sw};

        const float uu[8] = {ua.x, ua.y, ua.z, ua.w, ub.x, ub.y, ub.z, ub.w};
        const float vv[8] = {va.x, va.y, va.z, va.w, vb.x, vb.y, vb.z, vb.w};

        union { unsigned w[4]; short8 s; } B;
#pragma unroll
        for (int w = 0; w < 4; ++w) {
            v2f a = {uu[2 * w] + vv[2 * w], uu[2 * w + 1] + vv[2 * w + 1]};
            a = a + swp * w14p[w];             // contracts to pk_fma
            const v2f h = gelu2(a);
            B.w[w] = cvt_pk_bf16(h.x, h.y);
        }

        f32x4 acc = {0.f, 0.f, 0.f, 0.f};
        acc = __builtin_amdgcn_mfma_f32_16x16x32_bf16(A.s, B.s, acc, 0, 0, 0);

        // D: col = e16 = j-in-tile, row = kq*4+q = e  -> store rows 0..7
        if (kq < 2 && j < SEQ) {
            float* o = out + obb + (size_t)(kq * 4) * NPB + (size_t)i * SEQ + j;
#pragma unroll
            for (int q = 0; q < 4; ++q)
                o[(size_t)q * NPB] = acc[q] + b2v[q];
        }
    }
}

extern "C" void kernel_launch(void* const* d_in, const int* in_sizes, int n_in,
                              void* d_out, int out_size, void* d_ws, size_t ws_size,
                              hipStream_t stream) {
    const float* x       = (const float*)d_in[0];
    const float* piece_w = (const float*)d_in[1];
    const float* piece_b = (const float*)d_in[2];
    const float* color_w = (const float*)d_in[3];
    const float* color_b = (const float*)d_in[4];
    const float* mlp1_w  = (const float*)d_in[5];
    const float* mlp1_b  = (const float*)d_in[6];
    const float* mlp2_w  = (const float*)d_in[7];
    const float* mlp2_b  = (const float*)d_in[8];
    float* out = (float*)d_out;
    float* ws  = (float*)d_ws;   // 512*5776*4 = 11.83 MB

    hipLaunchKernelGGL(k1_embed, dim3(2048), dim3(256), 0, stream,
                       x, piece_w, piece_b, color_w, color_b, mlp1_w, mlp1_b, ws);
    hipLaunchKernelGGL(k2_pair, dim3(BATCHN * 3), dim3(256), 0, stream,
                       ws, mlp1_w, mlp2_w, mlp2_b, out);
}

// Round 7
// 86.204 us; speedup vs baseline: 1.7506x; 1.0040x over previous
//
#include <hip/hip_runtime.h>

#define SEQ 79
#define DM 1024
#define BATCHN 512
#define NROWS (BATCHN * SEQ)        // 40448
#define NPB (SEQ * SEQ)             // 6241
#define P 36                        // k-pitch in floats (16B-aligned rows)
#define UOFF 0
#define VOFF (SEQ * P)              // 2844
#define COFF2 (2 * SEQ * P)         // 5688 (col right after v)
#define WS_PER_B 5776               // padded; 23.1 KB per batch in global ws
#define NT32 237                    // 79 i * 3 j-tiles of 32 (last: 15 valid)
#define CH32 60                     // tiles per block chunk (4 blocks/batch)
#define K2LDS 2924                  // v[2844] + col[80] floats = 11,696 B

typedef float v2f   __attribute__((ext_vector_type(2)));
typedef float f32x4 __attribute__((ext_vector_type(4)));
typedef short short8 __attribute__((ext_vector_type(8)));

// ---------------- K1: per-(b,n) row -> u'[32], v'[32], color -------------
__global__ __launch_bounds__(256) void k1_embed(
    const float* __restrict__ x,
    const float* __restrict__ piece_w, const float* __restrict__ piece_b,
    const float* __restrict__ color_w, const float* __restrict__ color_b,
    const float* __restrict__ mlp1_w,  const float* __restrict__ mlp1_b,
    float* __restrict__ ws)
{
    const int lane = threadIdx.x & 63;
    const int wid  = (blockIdx.x * blockDim.x + threadIdx.x) >> 6;
    const int nw   = (gridDim.x * blockDim.x) >> 6;
    const int k    = lane & 31;
    const bool is_u = (lane < 32);

    float wp[4][4][7];
#pragma unroll
    for (int q = 0; q < 4; ++q)
#pragma unroll
        for (int t = 0; t < 4; ++t) {
            const int c = q * 256 + lane * 4 + t;
#pragma unroll
            for (int e = 0; e < 6; ++e) wp[q][t][e] = piece_w[c * 6 + e];
            wp[q][t][6] = color_w[c];
        }

    float wsp0 = mlp1_w[0 * 32 + k];
    float wsp1 = mlp1_w[1 * 32 + k];
    if (!is_u) { wsp0 = -wsp0; wsp1 = -wsp1; }
    const float bias1 = is_u ? mlp1_b[k] : 0.0f;
    float wc[6];
#pragma unroll
    for (int c = 0; c < 6; ++c)
        wc[c] = mlp1_w[((is_u ? 2 : 8) + c) * 32 + k];

    float pb[6];
#pragma unroll
    for (int e = 0; e < 6; ++e) pb[e] = piece_b[e];
    const float cb = color_b[0];

    for (int row = wid; row < NROWS; row += nw) {
        const float4* xr = (const float4*)(x + (size_t)row * DM);
        float4 xv[4];
#pragma unroll
        for (int q = 0; q < 4; ++q) xv[q] = xr[q * 64 + lane];

        float acc[7] = {0.f, 0.f, 0.f, 0.f, 0.f, 0.f, 0.f};
#pragma unroll
        for (int q = 0; q < 4; ++q) {
            const float xs[4] = {xv[q].x, xv[q].y, xv[q].z, xv[q].w};
#pragma unroll
            for (int t = 0; t < 4; ++t)
#pragma unroll
                for (int e = 0; e < 7; ++e)
                    acc[e] = fmaf(xs[t], wp[q][t][e], acc[e]);
        }

#pragma unroll
        for (int e = 0; e < 7; ++e) {
#pragma unroll
            for (int m = 32; m >= 1; m >>= 1)
                acc[e] += __shfl_xor(acc[e], m, 64);
        }

        float p[6];
#pragma unroll
        for (int e = 0; e < 6; ++e) p[e] = acc[e] + pb[e];

        const int b = row / SEQ;
        const int n = row - b * SEQ;
        const float fx = (n < 64) ? (float)(n >> 3) : 0.0f;
        const float fy = (n < 64) ? (float)(n & 7) : 0.0f;

        float val = bias1;
        val = fmaf(fx, wsp0, val);
        val = fmaf(fy, wsp1, val);
#pragma unroll
        for (int c = 0; c < 6; ++c) val = fmaf(p[c], wc[c], val);

        ws[(size_t)b * WS_PER_B + (is_u ? UOFF : VOFF) + n * P + k] = val;
        if (lane == 0) ws[(size_t)b * WS_PER_B + COFF2 + n] = acc[6] + cb;
    }
}

// ---------------- K2: 32-j tiles, packed gelu + MFMA layer-2 ----------
__device__ __forceinline__ unsigned cvt_pk_bf16(float lo, float hi) {
    unsigned r;
    asm("v_cvt_pk_bf16_f32 %0, %1, %2" : "=v"(r) : "v"(lo), "v"(hi));
    return r;
}

__device__ __forceinline__ v2f gelu2(v2f a) {
    const v2f C1 = {2.3022585093f, 2.3022585093f};
    const v2f C2 = {0.1029450750f, 0.1029450750f};
    v2f tt = a * (a * a * C2 + C1);
    v2f e;
    e.x = __builtin_amdgcn_exp2f(tt.x);
    e.y = __builtin_amdgcn_exp2f(tt.y);
    v2f ep = e + (v2f){1.f, 1.f};
    v2f r;
    r.x = __builtin_amdgcn_rcpf(ep.x);
    r.y = __builtin_amdgcn_rcpf(ep.y);
    return a - a * r;
}

__global__ __launch_bounds__(256, 8) void k2_pair(
    const float* __restrict__ ws,
    const float* __restrict__ mlp1_w,
    const float* __restrict__ mlp2_w, const float* __restrict__ mlp2_b,
    float* __restrict__ out)
{
    __shared__ float lds[K2LDS];        // 11,696 B -> 8 blocks/CU, 32 waves

    const int tid  = threadIdx.x;
    const int lane = tid & 63;
    const int wv   = tid >> 6;
    const int blk  = blockIdx.x;
    const int b    = blk >> 2;
    const int qq   = blk & 3;
    const float* wsb = ws + (size_t)b * WS_PER_B;

    const int e16 = lane & 15;          // j-in-subtile / output e
    const int kq  = lane >> 4;          // k-quarter
    const int k0  = kq * 8;

    // A-frag = W2^T (e rows 0..7; 8..15 zero), elem q <-> k0+q
    union { unsigned w[4]; short8 s; } A;
#pragma unroll
    for (int w = 0; w < 4; ++w) {
        const float lo = (e16 < 8) ? mlp2_w[(k0 + 2 * w) * 8 + e16] : 0.0f;
        const float hi = (e16 < 8) ? mlp2_w[(k0 + 2 * w + 1) * 8 + e16] : 0.0f;
        A.w[w] = cvt_pk_bf16(lo, hi);
    }
    v2f w14p[4];
#pragma unroll
    for (int w = 0; w < 4; ++w)
        w14p[w] = (v2f){mlp1_w[14 * 32 + k0 + 2 * w], mlp1_w[14 * 32 + k0 + 2 * w + 1]};
    float b2v[4];
#pragma unroll
    for (int q = 0; q < 4; ++q)
        b2v[q] = (kq < 2) ? mlp2_b[kq * 4 + q] : 0.0f;

    // ---- stage v + col (11.7 KB) into LDS
    {
        const float4* src = (const float4*)(wsb + VOFF);
        float4* dst = (float4*)lds;
#pragma unroll
        for (int s = 0; s < 3; ++s) {
            const int idx = tid + s * 256;
            if (idx < K2LDS / 4) dst[idx] = src[idx];
        }
    }
    __syncthreads();

    const float* vS = lds;              // [79][36]
    const float* cS = lds + 2844;       // [79]
    const float* uG = wsb + UOFF;       // global, wave-uniform reads
    const float* cG = wsb + COFF2;

    const int tstart = qq * CH32;
    const int tend   = (qq == 3) ? NT32 : tstart + CH32;
    const size_t obb = (size_t)b * (8 * NPB);

    for (int t = tstart + wv; t < tend; t += 4) {
        const int i  = t / 3;                  // wave-uniform
        const int jt = t - i * 3;
        const int j0 = jt * 32;
        const int js0 = j0 + e16;
        const int js1 = js0 + 16;
        const bool has1 = (jt < 2);            // jt==2: js1 >= 80, fully invalid

        // u (broadcast, global) + col[i]
        const float4 ua = *(const float4*)(uG + i * P + k0);
        const float4 ub = *(const float4*)(uG + i * P + k0 + 4);
        const float ci = cG[i];
        const float uu[8] = {ua.x, ua.y, ua.z, ua.w, ub.x, ub.y, ub.z, ub.w};

        // sub-tile 0
        const float4 va0 = *(const float4*)(vS + js0 * P + k0);
        const float4 vb0 = *(const float4*)(vS + js0 * P + k0 + 4);
        const float sw0 = (ci == cS[js0]) ? 1.0f : 0.0f;
        const v2f swp0 = {sw0, sw0};
        const float vv0[8] = {va0.x, va0.y, va0.z, va0.w, vb0.x, vb0.y, vb0.z, vb0.w};

        union { unsigned w[4]; short8 s; } B0;
#pragma unroll
        for (int w = 0; w < 4; ++w) {
            v2f a = {uu[2 * w] + vv0[2 * w], uu[2 * w + 1] + vv0[2 * w + 1]};
            a = a + swp0 * w14p[w];
            const v2f h = gelu2(a);
            B0.w[w] = cvt_pk_bf16(h.x, h.y);
        }
        f32x4 acc0 = {0.f, 0.f, 0.f, 0.f};
        acc0 = __builtin_amdgcn_mfma_f32_16x16x32_bf16(A.s, B0.s, acc0, 0, 0, 0);

        if (kq < 2 && js0 < SEQ) {
            float* o = out + obb + (size_t)(kq * 4) * NPB + (size_t)i * SEQ + js0;
#pragma unroll
            for (int q = 0; q < 4; ++q)
                o[(size_t)q * NPB] = acc0[q] + b2v[q];
        }

        // sub-tile 1
        if (has1) {
            const float4 va1 = *(const float4*)(vS + js1 * P + k0);
            const float4 vb1 = *(const float4*)(vS + js1 * P + k0 + 4);
            const float sw1 = (ci == cS[js1]) ? 1.0f : 0.0f;
            const v2f swp1 = {sw1, sw1};
            const float vv1[8] = {va1.x, va1.y, va1.z, va1.w, vb1.x, vb1.y, vb1.z, vb1.w};

            union { unsigned w[4]; short8 s; } B1;
#pragma unroll
            for (int w = 0; w < 4; ++w) {
                v2f a = {uu[2 * w] + vv1[2 * w], uu[2 * w + 1] + vv1[2 * w + 1]};
                a = a + swp1 * w14p[w];
                const v2f h = gelu2(a);
                B1.w[w] = cvt_pk_bf16(h.x, h.y);
            }
            f32x4 acc1 = {0.f, 0.f, 0.f, 0.f};
            acc1 = __builtin_amdgcn_mfma_f32_16x16x32_bf16(A.s, B1.s, acc1, 0, 0, 0);

            if (kq < 2) {   // js1 = 16..63 always < SEQ when has1
                float* o = out + obb + (size_t)(kq * 4) * NPB + (size_t)i * SEQ + js1;
#pragma unroll
                for (int q = 0; q < 4; ++q)
                    o[(size_t)q * NPB] = acc1[q] + b2v[q];
            }
        }
    }
}

extern "C" void kernel_launch(void* const* d_in, const int* in_sizes, int n_in,
                              void* d_out, int out_size, void* d_ws, size_t ws_size,
                              hipStream_t stream) {
    const float* x       = (const float*)d_in[0];
    const float* piece_w = (const float*)d_in[1];
    const float* piece_b = (const float*)d_in[2];
    const float* color_w = (const float*)d_in[3];
    const float* color_b = (const float*)d_in[4];
    const float* mlp1_w  = (const float*)d_in[5];
    const float* mlp1_b  = (const float*)d_in[6];
    const float* mlp2_w  = (const float*)d_in[7];
    const float* mlp2_b  = (const float*)d_in[8];
    float* out = (float*)d_out;
    float* ws  = (float*)d_ws;   // 512*5776*4 = 11.83 MB

    hipLaunchKernelGGL(k1_embed, dim3(2048), dim3(256), 0, stream,
                       x, piece_w, piece_b, color_w, color_b, mlp1_w, mlp1_b, ws);
    hipLaunchKernelGGL(k2_pair, dim3(BATCHN * 4), dim3(256), 0, stream,
                       ws, mlp1_w, mlp2_w, mlp2_b, out);
}

// Round 8
// 82.359 us; speedup vs baseline: 1.8323x; 1.0467x over previous
//
#include <hip/hip_runtime.h>

#define SEQ 79
#define DM 1024
#define BATCHN 512
#define NPB (SEQ * SEQ)             // 6241
#define P 36                        // k-pitch in floats (16B-aligned, odd/32 banks)
#define NST 395                     // 79 i * 5 j-subtiles of 16

typedef float v2f   __attribute__((ext_vector_type(2)));
typedef float f32x4 __attribute__((ext_vector_type(4)));
typedef short short8 __attribute__((ext_vector_type(8)));

__device__ __forceinline__ unsigned cvt_pk_bf16(float lo, float hi) {
    unsigned r;
    asm("v_cvt_pk_bf16_f32 %0, %1, %2" : "=v"(r) : "v"(lo), "v"(hi));
    return r;
}

__device__ __forceinline__ v2f gelu2(v2f a) {
    // gelu(a) = a - a / (exp2(c1*a + c2*a^3) + 1)
    const v2f C1 = {2.3022585093f, 2.3022585093f};
    const v2f C2 = {0.1029450750f, 0.1029450750f};
    v2f tt = a * (a * a * C2 + C1);
    v2f e;
    e.x = __builtin_amdgcn_exp2f(tt.x);
    e.y = __builtin_amdgcn_exp2f(tt.y);
    v2f ep = e + (v2f){1.f, 1.f};
    v2f r;
    r.x = __builtin_amdgcn_rcpf(ep.x);
    r.y = __builtin_amdgcn_rcpf(ep.y);
    return a - a * r;
}

// One block per batch. Phase A: 4 waves, one token row each per iteration;
// coalesced float4 x-loads, per-lane weight registers, butterfly reduce;
// u'/v'/col written straight to LDS. Phase B: 16-pair subtiles, packed-f32
// gelu, one mfma_f32_16x16x32_bf16 per subtile, coalesced 64B stores.
__global__ __launch_bounds__(256, 2) void fused_bias(
    const float* __restrict__ x,
    const float* __restrict__ piece_w, const float* __restrict__ piece_b,
    const float* __restrict__ color_w, const float* __restrict__ color_b,
    const float* __restrict__ mlp1_w,  const float* __restrict__ mlp1_b,
    const float* __restrict__ mlp2_w,  const float* __restrict__ mlp2_b,
    float* __restrict__ out)
{
    __shared__ float uL[80 * P];     // 11,520 B
    __shared__ float vL[80 * P];     // 11,520 B
    __shared__ float colL[80];       // row 79 of vL/colL never written; reads
                                     // of j==79 are discarded by store guards
    const int tid  = threadIdx.x;
    const int lane = tid & 63;
    const int wv   = tid >> 6;
    const int b    = blockIdx.x;
    const int k    = lane & 31;
    const bool is_u = (lane < 32);

    // ---- phase-A per-lane projection weights: c = q*256 + lane*4 + t
    float wp[4][4][7];
#pragma unroll
    for (int q = 0; q < 4; ++q)
#pragma unroll
        for (int t = 0; t < 4; ++t) {
            const int c = q * 256 + lane * 4 + t;
#pragma unroll
            for (int e = 0; e < 6; ++e) wp[q][t][e] = piece_w[c * 6 + e];
            wp[q][t][6] = color_w[c];
        }

    float wsp0 = mlp1_w[0 * 32 + k];
    float wsp1 = mlp1_w[1 * 32 + k];
    if (!is_u) { wsp0 = -wsp0; wsp1 = -wsp1; }
    const float bias1 = is_u ? mlp1_b[k] : 0.0f;
    float wc[6];
#pragma unroll
    for (int c = 0; c < 6; ++c)
        wc[c] = mlp1_w[((is_u ? 2 : 8) + c) * 32 + k];
    float pb[6];
#pragma unroll
    for (int e = 0; e < 6; ++e) pb[e] = piece_b[e];
    const float cb = color_b[0];

    // ---- phase-B lane constants
    const int e16 = lane & 15;          // j-in-subtile / W2 output index
    const int kq  = lane >> 4;          // k-quarter
    const int k0  = kq * 8;

    union { unsigned w[4]; short8 s; } A;   // A-frag = W2^T (rows 8..15 zero)
#pragma unroll
    for (int w = 0; w < 4; ++w) {
        const float lo = (e16 < 8) ? mlp2_w[(k0 + 2 * w) * 8 + e16] : 0.0f;
        const float hi = (e16 < 8) ? mlp2_w[(k0 + 2 * w + 1) * 8 + e16] : 0.0f;
        A.w[w] = cvt_pk_bf16(lo, hi);
    }
    v2f w14p[4];
#pragma unroll
    for (int w = 0; w < 4; ++w)
        w14p[w] = (v2f){mlp1_w[14 * 32 + k0 + 2 * w], mlp1_w[14 * 32 + k0 + 2 * w + 1]};
    float b2v[4];
#pragma unroll
    for (int q = 0; q < 4; ++q)
        b2v[q] = (kq < 2) ? mlp2_b[kq * 4 + q] : 0.0f;

    // ---------------- Phase A: 79 token rows -> LDS ----------------
    for (int n = wv; n < SEQ; n += 4) {
        const float4* xr = (const float4*)(x + ((size_t)b * SEQ + n) * DM);
        float4 xv[4];
#pragma unroll
        for (int q = 0; q < 4; ++q) xv[q] = xr[q * 64 + lane];

        float acc[7] = {0.f, 0.f, 0.f, 0.f, 0.f, 0.f, 0.f};
#pragma unroll
        for (int q = 0; q < 4; ++q) {
            const float xs[4] = {xv[q].x, xv[q].y, xv[q].z, xv[q].w};
#pragma unroll
            for (int t = 0; t < 4; ++t)
#pragma unroll
                for (int e = 0; e < 7; ++e)
                    acc[e] = fmaf(xs[t], wp[q][t][e], acc[e]);
        }

#pragma unroll
        for (int e = 0; e < 7; ++e) {
#pragma unroll
            for (int m = 32; m >= 1; m >>= 1)
                acc[e] += __shfl_xor(acc[e], m, 64);
        }

        float p[6];
#pragma unroll
        for (int e = 0; e < 6; ++e) p[e] = acc[e] + pb[e];

        const float fx = (n < 64) ? (float)(n >> 3) : 0.0f;
        const float fy = (n < 64) ? (float)(n & 7) : 0.0f;

        float val = bias1;
        val = fmaf(fx, wsp0, val);
        val = fmaf(fy, wsp1, val);
#pragma unroll
        for (int c = 0; c < 6; ++c) val = fmaf(p[c], wc[c], val);

        float* dst = is_u ? uL : vL;
        dst[n * P + k] = val;
        if (lane == 0) colL[n] = acc[6] + cb;
    }

    __syncthreads();

    // ---------------- Phase B: 395 subtiles of 16 pairs ----------------
    const size_t obb = (size_t)b * (8 * NPB);
    for (int st = wv; st < NST; st += 4) {
        const int i  = st / 5;             // wave-uniform
        const int jt = st - 5 * i;
        const int j  = jt * 16 + e16;      // 79 possible on last subtile

        const float4 ua = *(const float4*)(uL + i * P + k0);   // broadcast
        const float4 ub = *(const float4*)(uL + i * P + k0 + 4);
        const float ci = colL[i];
        const float4 va = *(const float4*)(vL + j * P + k0);   // stride-1
        const float4 vb = *(const float4*)(vL + j * P + k0 + 4);
        const float sw = (ci == colL[j]) ? 1.0f : 0.0f;
        const v2f swp = {sw, sw};

        const float uu[8] = {ua.x, ua.y, ua.z, ua.w, ub.x, ub.y, ub.z, ub.w};
        const float vv[8] = {va.x, va.y, va.z, va.w, vb.x, vb.y, vb.z, vb.w};

        union { unsigned w[4]; short8 s; } B;
#pragma unroll
        for (int w = 0; w < 4; ++w) {
            v2f a = {uu[2 * w] + vv[2 * w], uu[2 * w + 1] + vv[2 * w + 1]};
            a = a + swp * w14p[w];
            const v2f h = gelu2(a);
            B.w[w] = cvt_pk_bf16(h.x, h.y);
        }

        f32x4 acc2 = {0.f, 0.f, 0.f, 0.f};
        acc2 = __builtin_amdgcn_mfma_f32_16x16x32_bf16(A.s, B.s, acc2, 0, 0, 0);

        // D: col = e16 (j), row = kq*4+q (e); rows 0..7 valid
        if (kq < 2 && j < SEQ) {
            float* o = out + obb + (size_t)(kq * 4) * NPB + (size_t)i * SEQ + j;
#pragma unroll
            for (int q = 0; q < 4; ++q)
                o[(size_t)q * NPB] = acc2[q] + b2v[q];
        }
    }
}

extern "C" void kernel_launch(void* const* d_in, const int* in_sizes, int n_in,
                              void* d_out, int out_size, void* d_ws, size_t ws_size,
                              hipStream_t stream) {
    const float* x       = (const float*)d_in[0];
    const float* piece_w = (const float*)d_in[1];
    const float* piece_b = (const float*)d_in[2];
    const float* color_w = (const float*)d_in[3];
    const float* color_b = (const float*)d_in[4];
    const float* mlp1_w  = (const float*)d_in[5];
    const float* mlp1_b  = (const float*)d_in[6];
    const float* mlp2_w  = (const float*)d_in[7];
    const float* mlp2_b  = (const float*)d_in[8];
    float* out = (float*)d_out;

    hipLaunchKernelGGL(fused_bias, dim3(BATCHN), dim3(256), 0, stream,
                       x, piece_w, piece_b, color_w, color_b,
                       mlp1_w, mlp1_b, mlp2_w, mlp2_b, out);
}